// Round 1
// baseline (12297.379 us; speedup 1.0000x reference)
//
#include <hip/hip_runtime.h>

// LSTM: B=64, S=512, D=H=O=1024.
// R3 change: the 512 sequential k_step launches (7.7 us/step, launch/latency
// bound) are replaced by ONE persistent kernel that:
//   - stages each block's 16 Wh rows into LDS once (kept for all 512 steps)
//   - keeps c-state in registers across steps (one (row,k) per thread)
//   - reads h_prev fragments directly from global (cache-hot, no LDS staging)
//   - prefetches xg_t before the MFMA loop
//   - separates steps with a 2-level device-scope grid barrier (monotonic
//     counters in d_out scratch, later overwritten by the y-GEMM)
//
// Pipeline:
//  1) convert x -> bf16 [s][b][d]
//  2) pack Wx,Wh -> bf16 gate-interleaved rows n' = k*4 + gate
//  3) xg = x @ Wx^T  (bf16 MFMA GEMM, 32768x4096x1024), stored bf16
//  4) persistent recurrence kernel: 512 steps, grid barrier between steps
//  5) y = h_all @ Wp^T  (32768x1024x1024), scattered to out[b][s][o]
//  6) tail: final (c,h) f32 -> out

typedef unsigned short u16;
typedef u16   u16x4  __attribute__((ext_vector_type(4)));
typedef u16   u16x8  __attribute__((ext_vector_type(8)));
typedef __bf16 bf16x8 __attribute__((ext_vector_type(8)));
typedef float f32x4  __attribute__((ext_vector_type(4)));

__device__ __forceinline__ u16 f2bf(float x) {
    unsigned u = __float_as_uint(x);
    u = (u + 0x7FFFu + ((u >> 16) & 1u)) >> 16;   // RNE
    return (u16)u;
}
__device__ __forceinline__ float bf2f(u16 h) {
    return __uint_as_float(((unsigned)h) << 16);
}
__device__ __forceinline__ float fsig(float x) { return 1.f / (1.f + __expf(-x)); }
__device__ __forceinline__ float ftanh(float x) { return 1.f - 2.f / (__expf(2.f * x) + 1.f); }

// ---- conversion / packing kernels -----------------------------------------

// x[b][s][d] f32 -> xb[(s*64+b)][d] bf16.  grid = B*S blocks, 256 thr.
__global__ void k_convert_x(const float* __restrict__ x, u16* __restrict__ xb) {
    int bi = blockIdx.x;            // = b*512 + s  (x row order)
    int b = bi >> 9, s = bi & 511;
    const float4* src = (const float4*)(x + (size_t)bi * 1024);
    u16* dst = xb + ((size_t)(s * 64 + b)) * 1024;
    int t = threadIdx.x;
    float4 v = src[t];
    u16x4 o; o.x = f2bf(v.x); o.y = f2bf(v.y); o.z = f2bf(v.z); o.w = f2bf(v.w);
    *(u16x4*)(dst + t * 4) = o;
}

// W[4][1024][1024] f32 -> wp[n'=k*4+g][1024] bf16.  grid = 4096 blocks.
__global__ void k_pack_gates(const float* __restrict__ w, u16* __restrict__ wp) {
    int np = blockIdx.x;
    int g = np & 3, k = np >> 2;
    const float4* src = (const float4*)(w + ((size_t)(g * 1024 + k)) * 1024);
    u16* dst = wp + (size_t)np * 1024;
    int t = threadIdx.x;
    float4 v = src[t];
    u16x4 o; o.x = f2bf(v.x); o.y = f2bf(v.y); o.z = f2bf(v.z); o.w = f2bf(v.w);
    *(u16x4*)(dst + t * 4) = o;
}

// plain f32 -> bf16 copy (Wp). n must be multiple of 1024.
__global__ void k_f2bf(const float* __restrict__ src, u16* __restrict__ dst, int n) {
    int i = (blockIdx.x * 256 + threadIdx.x) * 4;
    if (i < n) {
        float4 v = *(const float4*)(src + i);
        u16x4 o; o.x = f2bf(v.x); o.y = f2bf(v.y); o.z = f2bf(v.z); o.w = f2bf(v.w);
        *(u16x4*)(dst + i) = o;
    }
}

// bias[n'] = bx[g][k] + bh[g][k], n' = k*4+g. 4096 elems. Also zeroes the
// grid-barrier scratch (bar[0..33]).
__global__ void k_bias(const float* __restrict__ bx, const float* __restrict__ bh,
                       float* __restrict__ bias, unsigned* __restrict__ bar) {
    int np = blockIdx.x * 256 + threadIdx.x;
    if (np < 34) bar[np] = 0u;
    int g = np & 3, k = np >> 2;
    bias[np] = bx[g * 1024 + k] + bh[g * 1024 + k];
}

// zero h[slot 0] and c state. 65536 elems each.
__global__ void k_init(u16* __restrict__ hall0, float* __restrict__ cstate) {
    int i = blockIdx.x * 256 + threadIdx.x;
    hall0[i] = 0;
    cstate[i] = 0.f;
}

// ---- generic 64x64-tile bf16 GEMM (C = A @ Bt^T) --------------------------
// A: [M][K] bf16 row-major. Bt: [N][K] bf16 row-major.
// mode 0: Cb[m*N + n] = bf16(acc)                      (xg precompute)
// mode 1: Cf[(b*S_ + s)*O_ + n] = acc + bp[n], m=s*64+b (output projection)
__global__ __launch_bounds__(256) void k_gemm64(
    const u16* __restrict__ A, const u16* __restrict__ Bt,
    int K, int N, int mode,
    u16* __restrict__ Cb,
    float* __restrict__ Cf, const float* __restrict__ bp, int S_, int O_) {
    __shared__ u16 As[64 * 72];   // +8 pad
    __shared__ u16 Bs[64 * 72];
    int mb = blockIdx.x, nb = blockIdx.y;
    int tid = threadIdx.x, w = tid >> 6, lane = tid & 63;
    f32x4 acc[4] = {};
    int kchunks = K >> 6;
    for (int kc = 0; kc < kchunks; ++kc) {
        int k0 = kc * 64;
#pragma unroll
        for (int r = 0; r < 2; ++r) {
            int c = tid + 256 * r;            // 0..511: 16B chunks
            int row = c >> 3, kk = (c & 7) * 8;
            *(u16x8*)(&As[row * 72 + kk]) =
                *(const u16x8*)(A + (size_t)(mb * 64 + row) * K + k0 + kk);
            *(u16x8*)(&Bs[row * 72 + kk]) =
                *(const u16x8*)(Bt + (size_t)(nb * 64 + row) * K + k0 + kk);
        }
        __syncthreads();
#pragma unroll
        for (int kk = 0; kk < 64; kk += 32) {
            bf16x8 a = *(const bf16x8*)(&As[(w * 16 + (lane & 15)) * 72 + kk + (lane >> 4) * 8]);
#pragma unroll
            for (int nt = 0; nt < 4; ++nt) {
                bf16x8 b = *(const bf16x8*)(&Bs[(nt * 16 + (lane & 15)) * 72 + kk + (lane >> 4) * 8]);
                acc[nt] = __builtin_amdgcn_mfma_f32_16x16x32_bf16(a, b, acc[nt], 0, 0, 0);
            }
        }
        __syncthreads();
    }
    int q = lane >> 4, cl = lane & 15;
    if (mode == 0) {
#pragma unroll
        for (int nt = 0; nt < 4; ++nt)
#pragma unroll
            for (int j = 0; j < 4; ++j) {
                int m = mb * 64 + w * 16 + q * 4 + j;
                int n = nb * 64 + nt * 16 + cl;
                Cb[(size_t)m * N + n] = f2bf(acc[nt][j]);
            }
    } else {
#pragma unroll
        for (int nt = 0; nt < 4; ++nt)
#pragma unroll
            for (int j = 0; j < 4; ++j) {
                int m = mb * 64 + w * 16 + q * 4 + j;
                int n = nb * 64 + nt * 16 + cl;
                int b = m & 63, s = m >> 6;
                Cf[((size_t)b * S_ + s) * O_ + n] = acc[nt][j] + bp[n];
            }
    }
}

// ---- persistent recurrence kernel -----------------------------------------
// 256 blocks x 256 threads, one block per 16 gate-interleaved cols
// (= 4 k-values x 4 gates). Loops over all 512 steps with a device-scope
// grid barrier between steps. Wh tile (16x1024 bf16, 32KB) lives in LDS for
// the whole kernel; c-state lives in a register per thread.
//
// Residency: LDS 38KB (<160KB), 256 threads; every block fits a CU alone, so
// with 256 blocks on 256 CUs all blocks are co-resident -> spin barrier safe.
__global__ __launch_bounds__(256) void k_steps(
    const u16* __restrict__ whp,     // [4096][1024] bf16, gate-interleaved
    const u16* __restrict__ xg,      // [512][64][4096] bf16
    const float* __restrict__ bias,  // [4096]
    float* __restrict__ cstate,      // [64][1024] f32 (final c out)
    float* __restrict__ hf32,        // [64][1024] f32 (final h out)
    u16* __restrict__ hall,          // [513][64][1024] bf16
    unsigned* __restrict__ bar) {    // [34] barrier scratch (in d_out)
    __shared__ u16 Bs[16 * 1032];    // Wh rows, +8 pad: 2-way banks only
    __shared__ float glds[64 * 20];
    int nb = blockIdx.x;             // 0..255
    int tid = threadIdx.x, w = tid >> 6, lane = tid & 63;
    int q = lane >> 4, cl = lane & 15;

    // stage this block's 16 Wh rows once: 2048 x 16B chunks, 8 per thread
#pragma unroll
    for (int r = 0; r < 8; ++r) {
        int c = tid + 256 * r;            // 0..2047
        int row = c >> 7, kk = (c & 127) * 8;
        *(u16x8*)(&Bs[row * 1032 + kk]) =
            *(const u16x8*)(whp + (size_t)(nb * 16 + row) * 1024 + kk);
    }
    float biasv = bias[nb * 16 + cl];
    int erow = tid >> 2, ekv = tid & 3, ek = nb * 4 + ekv;
    float creg = 0.f;                 // c for (erow, ek), all 512 steps
    int boff = cl * 1032 + q * 8;
    __syncthreads();

    for (int t = 0; t < 512; ++t) {
        const u16* hp  = hall + (size_t)t * 65536;
        const u16* xgt = xg + (size_t)t * 262144;   // 64*4096
        // prefetch xg_t for this thread's 4 output rows (hides HBM latency)
        float xv[4];
#pragma unroll
        for (int j = 0; j < 4; ++j)
            xv[j] = bf2f(xgt[(size_t)(w * 16 + q * 4 + j) * 4096 + nb * 16 + cl]);

        // h @ Wh^T for this wave's 16 rows x block's 16 cols, K=1024
        const u16* arow = hp + (size_t)(w * 16 + cl) * 1024 + q * 8;
        f32x4 acc0 = {}, acc1 = {};
#pragma unroll
        for (int kk = 0; kk < 1024; kk += 64) {
            bf16x8 a0 = *(const bf16x8*)(arow + kk);
            bf16x8 b0 = *(const bf16x8*)(&Bs[boff + kk]);
            acc0 = __builtin_amdgcn_mfma_f32_16x16x32_bf16(a0, b0, acc0, 0, 0, 0);
            bf16x8 a1 = *(const bf16x8*)(arow + kk + 32);
            bf16x8 b1 = *(const bf16x8*)(&Bs[boff + kk + 32]);
            acc1 = __builtin_amdgcn_mfma_f32_16x16x32_bf16(a1, b1, acc1, 0, 0, 0);
        }
#pragma unroll
        for (int j = 0; j < 4; ++j)
            glds[(w * 16 + q * 4 + j) * 20 + cl] = acc0[j] + acc1[j] + xv[j] + biasv;
        __syncthreads();

        // gate math: one (row, k) per thread; c stays in register
        {
            float4 gv = *(const float4*)(&glds[erow * 20 + ekv * 4]);
            float ig = fsig(gv.x), fg = fsig(gv.y), og = fsig(gv.z), cc = ftanh(gv.w);
            float c_new = fg * creg + ig * cc;
            creg = c_new;
            float h = og * ftanh(c_new);
            hall[(size_t)(t + 1) * 65536 + erow * 1024 + ek] = f2bf(h);
            if (t == 511) {
                cstate[erow * 1024 + ek] = c_new;
                hf32[erow * 1024 + ek]   = h;
            }
        }

        if (t < 511) {
            __syncthreads();   // all stores of this block issued (vmcnt drain)
            if (tid == 0) {
                __builtin_amdgcn_fence(__ATOMIC_RELEASE, "agent");  // flush L2
                unsigned o1 = __hip_atomic_fetch_add(&bar[nb >> 3], 1u,
                        __ATOMIC_RELAXED, __HIP_MEMORY_SCOPE_AGENT);
                if (o1 == (unsigned)(8 * (t + 1) - 1)) {            // last of 8
                    unsigned o2 = __hip_atomic_fetch_add(&bar[32], 1u,
                            __ATOMIC_RELAXED, __HIP_MEMORY_SCOPE_AGENT);
                    if (o2 == (unsigned)(32 * (t + 1) - 1))         // last of 32
                        __hip_atomic_store(&bar[33], (unsigned)(t + 1),
                                __ATOMIC_RELAXED, __HIP_MEMORY_SCOPE_AGENT);
                }
                while (__hip_atomic_load(&bar[33], __ATOMIC_RELAXED,
                                         __HIP_MEMORY_SCOPE_AGENT)
                       < (unsigned)(t + 1))
                    __builtin_amdgcn_s_sleep(1);
            }
            __syncthreads();
            __builtin_amdgcn_fence(__ATOMIC_ACQUIRE, "agent");  // inv stale $
        }
    }
}

// final (c,h) -> d_out tail. 131072 elems.
__global__ void k_tail(const float* __restrict__ cstate, const float* __restrict__ hf32,
                       float* __restrict__ out) {
    int i = blockIdx.x * 256 + threadIdx.x;
    if (i < 65536) out[33554432 + i] = cstate[i];
    else           out[33554432 + i] = hf32[i - 65536];
}

extern "C" void kernel_launch(void* const* d_in, const int* in_sizes, int n_in,
                              void* d_out, int out_size, void* d_ws, size_t ws_size,
                              hipStream_t stream) {
    const float* x  = (const float*)d_in[0];
    const float* Wx = (const float*)d_in[1];
    const float* bx = (const float*)d_in[2];
    const float* Wh = (const float*)d_in[3];
    const float* bh = (const float*)d_in[4];
    const float* Wp = (const float*)d_in[5];
    const float* bp = (const float*)d_in[6];
    float* out = (float*)d_out;
    char* ws = (char*)d_ws;

    // workspace layout (bytes), total ~422 MB
    u16*   xb   = (u16*)  (ws);                   // 64 MB  [32768][1024] bf16
    u16*   wxp  = (u16*)  (ws + 67108864);        // 8 MB   [4096][1024]
    u16*   whp  = (u16*)  (ws + 75497472);        // 8 MB   [4096][1024]
    u16*   wpb  = (u16*)  (ws + 83886080);        // 2 MB   [1024][1024]
    float* bias = (float*)(ws + 85983232);        // 16 KB  [4096]
    float* cst  = (float*)(ws + 85999616);        // 256 KB [64][1024]
    float* hf32 = (float*)(ws + 86261760);        // 256 KB [64][1024]
    u16*   xg   = (u16*)  (ws + 86523904);        // 256 MB [32768][4096]
    u16*   hall = (u16*)  (ws + 354959360);       // 64.1 MB [513][64][1024]
    // grid-barrier scratch lives at the head of d_out (overwritten by y-GEMM)
    unsigned* bar = (unsigned*)d_out;

    k_convert_x<<<32768, 256, 0, stream>>>(x, xb);
    k_pack_gates<<<4096, 256, 0, stream>>>(Wx, wxp);
    k_pack_gates<<<4096, 256, 0, stream>>>(Wh, whp);
    k_f2bf<<<1024, 256, 0, stream>>>(Wp, wpb, 1048576);
    k_bias<<<16, 256, 0, stream>>>(bx, bh, bias, bar);
    k_init<<<256, 256, 0, stream>>>(hall, cst);

    // xg = x @ Wx^T : M=32768, N=4096, K=1024
    k_gemm64<<<dim3(512, 64), 256, 0, stream>>>(xb, wxp, 1024, 4096, 0,
                                                xg, nullptr, nullptr, 0, 0);
    // persistent recurrence: all 512 steps in one kernel
    k_steps<<<256, 256, 0, stream>>>(whp, xg, bias, cst, hf32, hall, bar);
    // y = h_all @ Wp^T : M=32768, N=1024, K=1024; scatter to out[b][s][o]
    k_gemm64<<<dim3(512, 16), 256, 0, stream>>>(hall + 65536, wpb, 1024, 1024, 1,
                                                nullptr, out, bp, 512, 1024);
    k_tail<<<512, 256, 0, stream>>>(cst, hf32, out);
}

// Round 3
// 8125.265 us; speedup vs baseline: 1.5135x; 1.5135x over previous
//
#include <hip/hip_runtime.h>

// LSTM: B=64, S=512, D=H=O=1024.
// R5: hardened fence-free persistent recurrence + m97-style 128x128 GEMM.
//  k_steps (64 blocks x 256 thr, Wh resident in LDS, c in registers):
//   - h stores: relaxed agent atomic 8B stores (sc1 write-through past the
//     non-coherent per-XCD L2 to the memory-side coherence point)
//   - h loads:  relaxed agent atomic 8B loads (sc1, always fresh at the
//     coherence point; immune to stale L1/L2 lines and compiler hoisting)
//   - release = s_waitcnt vmcnt(0); NO cache-maintenance ops anywhere
//   - grid barrier: 8x8 monotonic counter tree + spin w/ ~1s timeout escape
//   - next-step xg fragment prefetched before the barrier (hides under spin)
//  k_gemm128: 128x128 tile, BK=64, 4 waves, linear LDS,
//   __builtin_amdgcn_global_load_lds width=16 (m97 structure, ~870 TF).
//
// Pipeline:
//  1) convert x -> bf16 [s][b][d]
//  2) pack Wx,Wh -> bf16 gate-interleaved rows n' = k*4 + gate
//  3) xg = x @ Wx^T  (32768x4096x1024 bf16 MFMA), stored bf16
//  4) persistent recurrence kernel: 512 steps, fence-free grid barrier
//  5) y = h_all @ Wp^T (32768x1024x1024), scattered to out[b][s][o]
//  6) tail: final (c,h) f32 -> out

typedef unsigned short u16;
typedef unsigned long long u64;
typedef u16   u16x4  __attribute__((ext_vector_type(4)));
typedef u16   u16x8  __attribute__((ext_vector_type(8)));
typedef __bf16 bf16x8 __attribute__((ext_vector_type(8)));
typedef float f32x4  __attribute__((ext_vector_type(4)));

__device__ __forceinline__ u16 f2bf(float x) {
    unsigned u = __float_as_uint(x);
    u = (u + 0x7FFFu + ((u >> 16) & 1u)) >> 16;   // RNE
    return (u16)u;
}
__device__ __forceinline__ float bf2f(u16 h) {
    return __uint_as_float(((unsigned)h) << 16);
}
__device__ __forceinline__ float fsig(float x) { return 1.f / (1.f + __expf(-x)); }
__device__ __forceinline__ float ftanh(float x) { return 1.f - 2.f / (__expf(2.f * x) + 1.f); }

// async global->LDS, 16B per lane. ldsptr must be wave-uniform; HW writes
// ldsptr + lane*16 from each lane's gptr.
__device__ __forceinline__ void gload_lds16(const u16* g, u16* l) {
    __builtin_amdgcn_global_load_lds(
        (const __attribute__((address_space(1))) unsigned*)g,
        (__attribute__((address_space(3))) unsigned*)l, 16, 0, 0);
}

// ---- conversion / packing kernels -----------------------------------------

// x[b][s][d] f32 -> xb[(s*64+b)][d] bf16.  grid = B*S blocks, 256 thr.
__global__ void k_convert_x(const float* __restrict__ x, u16* __restrict__ xb) {
    int bi = blockIdx.x;            // = b*512 + s  (x row order)
    int b = bi >> 9, s = bi & 511;
    const float4* src = (const float4*)(x + (size_t)bi * 1024);
    u16* dst = xb + ((size_t)(s * 64 + b)) * 1024;
    int t = threadIdx.x;
    float4 v = src[t];
    u16x4 o; o.x = f2bf(v.x); o.y = f2bf(v.y); o.z = f2bf(v.z); o.w = f2bf(v.w);
    *(u16x4*)(dst + t * 4) = o;
}

// W[4][1024][1024] f32 -> wp[n'=k*4+g][1024] bf16.  grid = 4096 blocks.
__global__ void k_pack_gates(const float* __restrict__ w, u16* __restrict__ wp) {
    int np = blockIdx.x;
    int g = np & 3, k = np >> 2;
    const float4* src = (const float4*)(w + ((size_t)(g * 1024 + k)) * 1024);
    u16* dst = wp + (size_t)np * 1024;
    int t = threadIdx.x;
    float4 v = src[t];
    u16x4 o; o.x = f2bf(v.x); o.y = f2bf(v.y); o.z = f2bf(v.z); o.w = f2bf(v.w);
    *(u16x4*)(dst + t * 4) = o;
}

// plain f32 -> bf16 copy (Wp). n must be multiple of 1024.
__global__ void k_f2bf(const float* __restrict__ src, u16* __restrict__ dst, int n) {
    int i = (blockIdx.x * 256 + threadIdx.x) * 4;
    if (i < n) {
        float4 v = *(const float4*)(src + i);
        u16x4 o; o.x = f2bf(v.x); o.y = f2bf(v.y); o.z = f2bf(v.z); o.w = f2bf(v.w);
        *(u16x4*)(dst + i) = o;
    }
}

// bias[n'] = bx[g][k] + bh[g][k], n' = k*4+g. 4096 elems. Also zeroes the
// grid-barrier scratch (bar[0..33]).
__global__ void k_bias(const float* __restrict__ bx, const float* __restrict__ bh,
                       float* __restrict__ bias, unsigned* __restrict__ bar) {
    int np = blockIdx.x * 256 + threadIdx.x;
    if (np < 34) bar[np] = 0u;
    int g = np & 3, k = np >> 2;
    bias[np] = bx[g * 1024 + k] + bh[g * 1024 + k];
}

// zero h[slot 0] and c state. 65536 elems each.
__global__ void k_init(u16* __restrict__ hall0, float* __restrict__ cstate) {
    int i = blockIdx.x * 256 + threadIdx.x;
    hall0[i] = 0;
    cstate[i] = 0.f;
}

// ---- 128x128-tile bf16 GEMM (C = A @ Bt^T), m97 structure -----------------
// A: [M][K] bf16 row-major. Bt: [N][K] bf16 row-major. K % 64 == 0.
// 4 waves in 2x2; wave owns 64x64 out (acc[4][4] f32x4). Linear LDS
// [128][64] bf16 per operand, filled by global_load_lds width 16.
// mode 0: Cb[m*N + n] = bf16(acc)                      (xg precompute)
// mode 1: Cf[(b*S_ + s)*O_ + n] = acc + bp[n], m=s*64+b (output projection)
__global__ __launch_bounds__(256) void k_gemm128(
    const u16* __restrict__ A, const u16* __restrict__ Bt,
    int K, int N, int mode,
    u16* __restrict__ Cb,
    float* __restrict__ Cf, const float* __restrict__ bp, int S_, int O_) {
    __shared__ u16 As[128 * 64];   // 16 KB, linear (global_load_lds dest)
    __shared__ u16 Bs[128 * 64];   // 16 KB
    int mb = blockIdx.x, nb = blockIdx.y;
    int tid = threadIdx.x, w = tid >> 6, lane = tid & 63;
    int wr = w >> 1, wc = w & 1;
    int lr = lane >> 3, lc = lane & 7;     // staging: 8 rows x 8 chunks
    f32x4 acc[4][4] = {};
    for (int kc = 0; kc < (K >> 6); ++kc) {
        int k0 = kc * 64;
        // stage: wave w covers rows w*32..w*32+31 of both operands
#pragma unroll
        for (int i = 0; i < 4; ++i) {
            int row = w * 32 + i * 8;
            gload_lds16(A + (size_t)(mb * 128 + row + lr) * K + k0 + lc * 8,
                        As + row * 64);
            gload_lds16(Bt + (size_t)(nb * 128 + row + lr) * K + k0 + lc * 8,
                        Bs + row * 64);
        }
        __syncthreads();   // compiler emits vmcnt(0) drain before barrier
#pragma unroll
        for (int kk = 0; kk < 64; kk += 32) {
            bf16x8 af[4], bf[4];
#pragma unroll
            for (int mt = 0; mt < 4; ++mt)
                af[mt] = *(const bf16x8*)(&As[(wr * 64 + mt * 16 + (lane & 15)) * 64 +
                                              kk + (lane >> 4) * 8]);
#pragma unroll
            for (int nt = 0; nt < 4; ++nt)
                bf[nt] = *(const bf16x8*)(&Bs[(wc * 64 + nt * 16 + (lane & 15)) * 64 +
                                              kk + (lane >> 4) * 8]);
#pragma unroll
            for (int mt = 0; mt < 4; ++mt)
#pragma unroll
                for (int nt = 0; nt < 4; ++nt)
                    acc[mt][nt] = __builtin_amdgcn_mfma_f32_16x16x32_bf16(
                        af[mt], bf[nt], acc[mt][nt], 0, 0, 0);
        }
        __syncthreads();
    }
    int q = lane >> 4, cl = lane & 15;
    if (mode == 0) {
#pragma unroll
        for (int mt = 0; mt < 4; ++mt)
#pragma unroll
            for (int nt = 0; nt < 4; ++nt)
#pragma unroll
                for (int j = 0; j < 4; ++j) {
                    int m = mb * 128 + wr * 64 + mt * 16 + q * 4 + j;
                    int n = nb * 128 + wc * 64 + nt * 16 + cl;
                    Cb[(size_t)m * N + n] = f2bf(acc[mt][nt][j]);
                }
    } else {
#pragma unroll
        for (int mt = 0; mt < 4; ++mt)
#pragma unroll
            for (int nt = 0; nt < 4; ++nt)
#pragma unroll
                for (int j = 0; j < 4; ++j) {
                    int m = mb * 128 + wr * 64 + mt * 16 + q * 4 + j;
                    int n = nb * 128 + wc * 64 + nt * 16 + cl;
                    int b = m & 63, s = m >> 6;
                    Cf[((size_t)b * S_ + s) * O_ + n] = acc[mt][nt][j] + bp[n];
                }
    }
}

// ---- persistent recurrence kernel (fence-free, sc1-coherent) --------------
// 64 blocks x 256 threads. Block nb owns gate-cols n' = nb*64..+63
// (= k-values nb*16..nb*16+15, all 4 gates). Wh tile (64x1024 bf16) lives in
// LDS for the whole kernel; c-state lives in registers (float4 per thread).
// All cross-block h traffic goes through sc1 (agent-scope) loads AND stores:
// write-through to the coherence point, reads served from it. No fences.
//
// Residency: LDS ~146KB -> 1 block/CU; 64 blocks on 256 CUs, all co-resident
// -> spin barrier safe (plus timeout escape).
__global__ __launch_bounds__(256, 1) void k_steps(
    const u16* __restrict__ whp,     // [4096][1024] bf16, gate-interleaved
    const u16* __restrict__ xg,      // [512][64][4096] bf16
    const float* __restrict__ bias,  // [4096]
    float* __restrict__ cstate,      // [64][1024] f32 (final c out)
    float* __restrict__ hf32,        // [64][1024] f32 (final h out)
    u16* __restrict__ hall,          // [513][64][1024] bf16
    unsigned* __restrict__ bar) {    // [34] barrier scratch (in d_out)
    __shared__ u16 Bs[64 * 1032];    // Wh rows (block's 64 cols), 132096 B
    __shared__ float glds[64 * 68];  // gate staging, 17408 B
    int nb = blockIdx.x;             // 0..63
    int tid = threadIdx.x, w = tid >> 6, lane = tid & 63;
    int q = lane >> 4, cl = lane & 15;

    // stage this block's 64 Wh rows once: 8192 x 16B chunks, 32 per thread
#pragma unroll
    for (int r = 0; r < 32; ++r) {
        int c = tid + 256 * r;            // 0..8191
        int row = c >> 7, kk = (c & 127) * 8;
        *(u16x8*)(&Bs[row * 1032 + kk]) =
            *(const u16x8*)(whp + (size_t)(nb * 64 + row) * 1024 + kk);
    }
    float biasv[4];
#pragma unroll
    for (int nt = 0; nt < 4; ++nt) biasv[nt] = bias[nb * 64 + nt * 16 + cl];
    int grow = tid >> 2, gkq = tid & 3;   // gate-phase: row 0..63, k-quad 0..3
    int kbase = nb * 16 + gkq * 4;        // 4 consecutive k per thread
    f32x4 creg = {0.f, 0.f, 0.f, 0.f};    // c-state, lives here all 512 steps
    // xg fragment for t=0 (prefetched; later steps prefetch under the barrier)
    const u16* xgp0 = xg + (size_t)grow * 4096 + nb * 64 + gkq * 16;
    u16x8 xv0 = *(const u16x8*)(xgp0);
    u16x8 xv1 = *(const u16x8*)(xgp0 + 8);
    __syncthreads();

    for (int t = 0; t < 512; ++t) {
        const u16* hp = hall + (size_t)t * 65536;
        // h @ Wh^T : wave w -> rows w*16..+15, block cols 64, K=1024.
        // A-fragments read with sc1 (agent atomic) -> always coherent.
        const u16* arow = hp + (size_t)(w * 16 + cl) * 1024 + q * 8;
        f32x4 acc[4] = {};
#pragma unroll 8
        for (int kk = 0; kk < 1024; kk += 32) {
            union { u64 qw[2]; bf16x8 v; } au;
            au.qw[0] = __hip_atomic_load((const u64*)(arow + kk), __ATOMIC_RELAXED,
                                         __HIP_MEMORY_SCOPE_AGENT);
            au.qw[1] = __hip_atomic_load((const u64*)(arow + kk + 4), __ATOMIC_RELAXED,
                                         __HIP_MEMORY_SCOPE_AGENT);
#pragma unroll
            for (int nt = 0; nt < 4; ++nt) {
                bf16x8 b = *(const bf16x8*)(&Bs[(nt * 16 + cl) * 1032 + kk + q * 8]);
                acc[nt] = __builtin_amdgcn_mfma_f32_16x16x32_bf16(au.v, b, acc[nt], 0, 0, 0);
            }
        }
#pragma unroll
        for (int nt = 0; nt < 4; ++nt)
#pragma unroll
            for (int j = 0; j < 4; ++j)
                glds[(w * 16 + q * 4 + j) * 68 + nt * 16 + cl] = acc[nt][j] + biasv[nt];
        __syncthreads();

        // gate math: thread handles (row=grow, k = kbase..kbase+3)
        {
            const float* gp = &glds[grow * 68 + gkq * 16];
            float xf[16];
#pragma unroll
            for (int e = 0; e < 8; ++e) { xf[e] = bf2f(xv0[e]); xf[8 + e] = bf2f(xv1[e]); }
            u64 h64 = 0ull;
#pragma unroll
            for (int j = 0; j < 4; ++j) {
                float ig = fsig(gp[j * 4 + 0] + xf[j * 4 + 0]);
                float fg = fsig(gp[j * 4 + 1] + xf[j * 4 + 1]);
                float og = fsig(gp[j * 4 + 2] + xf[j * 4 + 2]);
                float cc = ftanh(gp[j * 4 + 3] + xf[j * 4 + 3]);
                float cn = fg * creg[j] + ig * cc;
                creg[j] = cn;
                float h = og * ftanh(cn);
                h64 |= (u64)f2bf(h) << (16 * j);
                if (t == 511) {
                    cstate[grow * 1024 + kbase + j] = cn;
                    hf32[grow * 1024 + kbase + j] = h;
                }
            }
            // write-through past non-coherent L2 (sc1), 8B per thread
            __hip_atomic_store(
                (u64*)(hall + (size_t)(t + 1) * 65536 + grow * 1024 + kbase),
                h64, __ATOMIC_RELAXED, __HIP_MEMORY_SCOPE_AGENT);
        }

        if (t < 511) {
            // prefetch next step's xg fragment; its latency hides under the
            // store-drain + barrier below (first use is next gate phase).
            const u16* xgp = xg + (size_t)(t + 1) * 262144 +
                             (size_t)grow * 4096 + nb * 64 + gkq * 16;
            xv0 = *(const u16x8*)(xgp);
            xv1 = *(const u16x8*)(xgp + 8);
            // release: drain this thread's write-through stores (and the
            // prefetch loads; both are one round trip, overlapped).
            asm volatile("s_waitcnt vmcnt(0)" ::: "memory");
            __syncthreads();                 // all 256 threads' h globally visible
            if (tid == 0) {
                unsigned o1 = __hip_atomic_fetch_add(&bar[nb >> 3], 1u,
                        __ATOMIC_RELAXED, __HIP_MEMORY_SCOPE_AGENT);
                if (o1 == (unsigned)(8 * (t + 1) - 1)) {            // last of 8
                    unsigned o2 = __hip_atomic_fetch_add(&bar[8], 1u,
                            __ATOMIC_RELAXED, __HIP_MEMORY_SCOPE_AGENT);
                    if (o2 == (unsigned)(8 * (t + 1) - 1))          // last of 8 groups
                        __hip_atomic_store(&bar[9], (unsigned)(t + 1),
                                __ATOMIC_RELAXED, __HIP_MEMORY_SCOPE_AGENT);
                }
                // spin with timeout escape (~1s) so a logic bug can't hang
                // the container; never triggers when all 64 blocks resident.
                int guard = 0;
                while (__hip_atomic_load(&bar[9], __ATOMIC_RELAXED,
                                         __HIP_MEMORY_SCOPE_AGENT)
                       < (unsigned)(t + 1)) {
                    __builtin_amdgcn_s_sleep(8);
                    if (++guard > (1 << 22)) break;
                }
            }
            __syncthreads();   // exec+memory barrier before next step's reads
        }
    }
}

// final (c,h) -> d_out tail. 131072 elems.
__global__ void k_tail(const float* __restrict__ cstate, const float* __restrict__ hf32,
                       float* __restrict__ out) {
    int i = blockIdx.x * 256 + threadIdx.x;
    if (i < 65536) out[33554432 + i] = cstate[i];
    else           out[33554432 + i] = hf32[i - 65536];
}

extern "C" void kernel_launch(void* const* d_in, const int* in_sizes, int n_in,
                              void* d_out, int out_size, void* d_ws, size_t ws_size,
                              hipStream_t stream) {
    const float* x  = (const float*)d_in[0];
    const float* Wx = (const float*)d_in[1];
    const float* bx = (const float*)d_in[2];
    const float* Wh = (const float*)d_in[3];
    const float* bh = (const float*)d_in[4];
    const float* Wp = (const float*)d_in[5];
    const float* bp = (const float*)d_in[6];
    float* out = (float*)d_out;
    char* ws = (char*)d_ws;

    // workspace layout (bytes), total ~422 MB
    u16*   xb   = (u16*)  (ws);                   // 64 MB  [32768][1024] bf16
    u16*   wxp  = (u16*)  (ws + 67108864);        // 8 MB   [4096][1024]
    u16*   whp  = (u16*)  (ws + 75497472);        // 8 MB   [4096][1024]
    u16*   wpb  = (u16*)  (ws + 83886080);        // 2 MB   [1024][1024]
    float* bias = (float*)(ws + 85983232);        // 16 KB  [4096]
    float* cst  = (float*)(ws + 85999616);        // 256 KB [64][1024]
    float* hf32 = (float*)(ws + 86261760);        // 256 KB [64][1024]
    u16*   xg   = (u16*)  (ws + 86523904);        // 256 MB [32768][4096]
    u16*   hall = (u16*)  (ws + 354959360);       // 64.1 MB [513][64][1024]
    // grid-barrier scratch lives at the head of d_out (overwritten by y-GEMM,
    // re-zeroed by k_bias inside the graph each replay)
    unsigned* bar = (unsigned*)d_out;

    k_convert_x<<<32768, 256, 0, stream>>>(x, xb);
    k_pack_gates<<<4096, 256, 0, stream>>>(Wx, wxp);
    k_pack_gates<<<4096, 256, 0, stream>>>(Wh, whp);
    k_f2bf<<<1024, 256, 0, stream>>>(Wp, wpb, 1048576);
    k_bias<<<16, 256, 0, stream>>>(bx, bh, bias, bar);
    k_init<<<256, 256, 0, stream>>>(hall, cst);

    // xg = x @ Wx^T : M=32768, N=4096, K=1024
    k_gemm128<<<dim3(256, 32), 256, 0, stream>>>(xb, wxp, 1024, 4096, 0,
                                                 xg, nullptr, nullptr, 0, 0);
    // persistent recurrence: all 512 steps in one kernel, fence-free
    k_steps<<<64, 256, 0, stream>>>(whp, xg, bias, cst, hf32, hall, bar);
    // y = h_all @ Wp^T : M=32768, N=1024, K=1024; scatter to out[b][s][o]
    k_gemm128<<<dim3(256, 8), 256, 0, stream>>>(hall + 65536, wpb, 1024, 1024, 1,
                                                nullptr, out, bp, 512, 1024);
    k_tail<<<512, 256, 0, stream>>>(cst, hf32, out);
}